// Round 5
// baseline (3065.582 us; speedup 1.0000x reference)
//
#include <hip/hip_runtime.h>
#include <cstdio>

#define HDIM 2048
#define NHEAD 16
#define DHEAD 128
#define BATCH 4
#define SEQ 2048
#define AUD 512

typedef unsigned short u16;
typedef unsigned int u32;
typedef __bf16 bf16_t;
typedef bf16_t bf16x8 __attribute__((ext_vector_type(8)));
typedef short short8 __attribute__((ext_vector_type(8)));
typedef float f32x4 __attribute__((ext_vector_type(4)));

__device__ __forceinline__ float b2f(u16 h) {
  union { u32 u; float f; } v; v.u = ((u32)h) << 16; return v.f;
}
__device__ __forceinline__ u16 f2b(float f) {
  union { float f; u32 u; } v; v.f = f;
  u32 r = (v.u + 0x7FFFu + ((v.u >> 16) & 1u)) >> 16;  // RNE
  return (u16)r;
}

// ---------------- f32 -> bf16 elementwise convert, 8 els/thread ----------------
__global__ __launch_bounds__(256) void cvt_k(const float* __restrict__ src,
                                             u16* __restrict__ dst, int n8) {
  int i = blockIdx.x * 256 + threadIdx.x;
  if (i >= n8) return;
  const float4* s4 = (const float4*)src;
  float4 a = s4[2 * i], b = s4[2 * i + 1];
  short8 o;
  o[0] = (short)f2b(a.x); o[1] = (short)f2b(a.y);
  o[2] = (short)f2b(a.z); o[3] = (short)f2b(a.w);
  o[4] = (short)f2b(b.x); o[5] = (short)f2b(b.y);
  o[6] = (short)f2b(b.z); o[7] = (short)f2b(b.w);
  *(short8*)(dst + (size_t)i * 8) = o;
}

// -------- weight transpose + convert: dst_bf16[n*2048 + k] = src_f32[k*2048 + n] --------
__global__ __launch_bounds__(256) void transpose_k(const float* __restrict__ src,
                                                   u16* __restrict__ dst) {
  __shared__ float tile[32][33];
  int tx = threadIdx.x, ty = threadIdx.y;        // 32 x 8
  int x = blockIdx.x * 32 + tx;
  int y0 = blockIdx.y * 32;
#pragma unroll
  for (int j = 0; j < 32; j += 8)
    tile[ty + j][tx] = src[(size_t)(y0 + ty + j) * HDIM + x];
  __syncthreads();
  int x2 = y0 + tx;
  int y2 = blockIdx.x * 32;
#pragma unroll
  for (int j = 0; j < 32; j += 8)
    dst[(size_t)(y2 + ty + j) * HDIM + x2] = f2b(tile[tx][ty + j]);
}

// ---------------- generic batched GEMM: C = alpha*(A @ B + bias), B given as BT rows --------
// A: [M,K] row-major (lda), BT: [N,K] row-major (ldb), bf16. bias f32 per column.
// batch z: ptr += (z>>4)*s?hi + (z&15)*s?lo (elements).
// cmode: 0 = bf16 C row-major; 1 = Vt scatter (bf16); 2 = f32 C row-major.
__global__ __launch_bounds__(256) void gemm_bt(
    const u16* __restrict__ A, int lda, long sAhi, long sAlo,
    const u16* __restrict__ Bt, int ldb, long sBhi, long sBlo,
    void* __restrict__ Cv, int ldc, long sChi, long sClo,
    const float* __restrict__ bias, float alpha, int M, int N, int K, int cmode) {
  int z = blockIdx.z;
  A += (size_t)(z >> 4) * sAhi + (size_t)(z & 15) * sAlo;
  Bt += (size_t)(z >> 4) * sBhi + (size_t)(z & 15) * sBlo;
  size_t coff = (size_t)(z >> 4) * sChi + (size_t)(z & 15) * sClo;

  int lane = threadIdx.x & 63;
  int wave = threadIdx.x >> 6;
  int n0 = blockIdx.x * 16;
  int m0 = (blockIdx.y * 4 + wave) * 16;
  int row = lane & 15;
  int quad = lane >> 4;

  const u16* ap = A + (size_t)(m0 + row) * lda + quad * 8;
  const u16* bp = Bt + (size_t)(n0 + row) * ldb + quad * 8;

  f32x4 acc = {0.f, 0.f, 0.f, 0.f};
  for (int k = 0; k < K; k += 32) {
    short8 ar = *(const short8*)(ap + k);
    short8 br = *(const short8*)(bp + k);
    acc = __builtin_amdgcn_mfma_f32_16x16x32_bf16(
        __builtin_bit_cast(bf16x8, ar), __builtin_bit_cast(bf16x8, br), acc, 0, 0, 0);
  }

  int nn = n0 + row;  // D: col = lane&15
  float bv = bias ? bias[nn] : 0.f;
#pragma unroll
  for (int r = 0; r < 4; r++) {
    int mm = m0 + quad * 4 + r;  // D: row = quad*4 + r
    float val = (acc[r] + bv) * alpha;
    if (cmode == 2) {
      ((float*)Cv)[coff + (size_t)mm * ldc + nn] = val;
    } else if (cmode == 1) {
      int bb = mm >> 9, aa = mm & 511;
      int hh = nn >> 7, dd = nn & 127;
      ((u16*)Cv)[((size_t)((bb * 16 + hh) * 128 + dd)) * 512 + aa] = f2b(val);
    } else {
      ((u16*)Cv)[coff + (size_t)mm * ldc + nn] = f2b(val);
    }
  }
}

// ------- softmax over 512 keys, one wave per (h,q) row of ONE batch, in place -------
__global__ __launch_bounds__(256) void softmax_k(u16* __restrict__ Sc,
                                                 const float* __restrict__ mp) {
  int g = blockIdx.x * 4 + (threadIdx.x >> 6);  // 0 .. NH*SEQ-1
  int lane = threadIdx.x & 63;
  u16* rowp = Sc + (size_t)g * AUD;
  float s[8];
  float mx = -3.0e38f;
#pragma unroll
  for (int i = 0; i < 8; i++) {
    int a = lane + 64 * i;
    float v = b2f(rowp[a]) + mp[a] * (-10000.0f);
    s[i] = v;
    mx = fmaxf(mx, v);
  }
  for (int off = 32; off; off >>= 1) mx = fmaxf(mx, __shfl_xor(mx, off, 64));
  float sum = 0.f;
#pragma unroll
  for (int i = 0; i < 8; i++) {
    s[i] = __expf(s[i] - mx);
    sum += s[i];
  }
  for (int off = 32; off; off >>= 1) sum += __shfl_xor(sum, off, 64);
  float inv = 1.0f / sum;
#pragma unroll
  for (int i = 0; i < 8; i++) rowp[lane + 64 * i] = f2b(s[i] * inv);
}

// ---- residual + LayerNorm (f32 in/out): out = LN(O + hs)*gamma + beta, in place ----
__global__ __launch_bounds__(256) void ln_k(const float* O,
                                            const float* __restrict__ hs,
                                            const float* __restrict__ gamma,
                                            const float* __restrict__ beta,
                                            float* out) {
  size_t rowoff = (size_t)blockIdx.x * HDIM;
  float x[8], sum = 0.f, sq = 0.f;
#pragma unroll
  for (int i = 0; i < 8; i++) {
    int idx = threadIdx.x + 256 * i;
    float v = O[rowoff + idx] + hs[rowoff + idx];
    x[i] = v;
    sum += v;
    sq += v * v;
  }
  for (int off = 32; off; off >>= 1) {
    sum += __shfl_xor(sum, off, 64);
    sq += __shfl_xor(sq, off, 64);
  }
  __shared__ float red[8];
  int wave = threadIdx.x >> 6, lane = threadIdx.x & 63;
  if (lane == 0) { red[wave] = sum; red[4 + wave] = sq; }
  __syncthreads();
  sum = red[0] + red[1] + red[2] + red[3];
  sq = red[4] + red[5] + red[6] + red[7];
  float mu = sum * (1.0f / HDIM);
  float var = sq * (1.0f / HDIM) - mu * mu;
  float inv = rsqrtf(var + 1e-5f);
#pragma unroll
  for (int i = 0; i < 8; i++) {
    int idx = threadIdx.x + 256 * i;
    out[rowoff + idx] = (x[i] - mu) * inv * gamma[idx] + beta[idx];
  }
}

extern "C" void kernel_launch(void* const* d_in, const int* in_sizes, int n_in,
                              void* d_out, int out_size, void* d_ws, size_t ws_size,
                              hipStream_t stream) {
  fprintf(stderr, "[diag] n_in=%d out_size=%d ws=%zu sizes:", n_in, out_size, ws_size);
  for (int i = 0; i < n_in; i++) fprintf(stderr, " %d", in_sizes[i]);
  fprintf(stderr, "\n");
  const float* hs   = (const float*)d_in[0];
  const float* at   = (const float*)d_in[1];
  const float* mask = (const float*)d_in[2];
  const float* Wq = (const float*)d_in[3];  const float* bq = (const float*)d_in[4];
  const float* Wk = (const float*)d_in[5];  const float* bk = (const float*)d_in[6];
  const float* Wv = (const float*)d_in[7];  const float* bv = (const float*)d_in[8];
  const float* Wo = (const float*)d_in[9];  const float* bo = (const float*)d_in[10];
  const float* gamma = (const float*)d_in[11];
  const float* beta  = (const float*)d_in[12];
  float* out = (float*)d_out;
  u16* ws = (u16*)d_ws;

  // workspace (bf16 elements). Total 83,886,080 els = 167.8 MB (ws has 256 MB).
  u16* hsb = ws;               // 16,777,216  bf16(hidden_states)
  u16* atb = ws + 16777216;    //  4,194,304  bf16(audio_tokens)
  u16* wT  = ws + 20971520;    //  4,194,304  transposed bf16 weight (reused 4x)
  u16* Q   = ws + 25165824;    // 16,777,216  (8192 x 2048)
  u16* Kb  = ws + 41943040;    //  4,194,304  (2048 x 2048)
  u16* Vt  = ws + 46137344;    //  4,194,304  [b,h,d,a]
  u16* Sc  = ws + 50331648;    // 16,777,216  (one batch: [h,q,a])
  u16* Ctx = ws + 67108864;    // 16,777,216  (8192 x 2048)
  // O (pre-LN, f32) lives in d_out; ln_k is same-thread in-place: safe.

  cvt_k<<<8192, 256, 0, stream>>>(hs, hsb, 2097152);
  cvt_k<<<2048, 256, 0, stream>>>(at, atb, 524288);

  dim3 tb(32, 8), tg(64, 64);
  const float qscale = 0.08838834764831845f;  // 1/sqrt(128)

  // Q = (hs @ Wq + bq) * qscale : M=8192 N=2048 K=2048
  transpose_k<<<tg, tb, 0, stream>>>(Wq, wT);
  gemm_bt<<<dim3(128, 128, 1), 256, 0, stream>>>(hsb, HDIM, 0, 0, wT, HDIM, 0, 0,
                                                 Q, HDIM, 0, 0, bq, qscale,
                                                 8192, 2048, 2048, 0);
  // K = at @ Wk + bk : M=2048
  transpose_k<<<tg, tb, 0, stream>>>(Wk, wT);
  gemm_bt<<<dim3(128, 32, 1), 256, 0, stream>>>(atb, HDIM, 0, 0, wT, HDIM, 0, 0,
                                                Kb, HDIM, 0, 0, bk, 1.0f,
                                                2048, 2048, 2048, 0);
  // V = at @ Wv + bv, written transposed per head into Vt
  transpose_k<<<tg, tb, 0, stream>>>(Wv, wT);
  gemm_bt<<<dim3(128, 32, 1), 256, 0, stream>>>(atb, HDIM, 0, 0, wT, HDIM, 0, 0,
                                                Vt, HDIM, 0, 0, bv, 1.0f,
                                                2048, 2048, 2048, 1);

  // attention per batch (Sc holds one batch at a time)
  for (int b = 0; b < BATCH; b++) {
    const u16* Qb = Q + (size_t)b * SEQ * HDIM;
    const u16* Kbb = Kb + (size_t)b * AUD * HDIM;
    const u16* Vtb = Vt + (size_t)b * NHEAD * DHEAD * AUD;
    u16* Ctxb = Ctx + (size_t)b * SEQ * HDIM;
    // scores[h] = Qh (2048x128) @ Kh^T : z = h, N=512, K=128
    gemm_bt<<<dim3(32, 32, NHEAD), 256, 0, stream>>>(
        Qb, HDIM, 0, DHEAD, Kbb, HDIM, 0, DHEAD,
        Sc, AUD, 0, (long)SEQ * AUD, nullptr, 1.0f, 2048, 512, 128, 0);
    // softmax rows (mask applied inside), in place
    softmax_k<<<NHEAD * SEQ / 4, 256, 0, stream>>>(Sc, mask + b * AUD);
    // ctx[h] = P (2048x512) @ V (512x128), BT = Vt rows : N=128, K=512
    gemm_bt<<<dim3(8, 32, NHEAD), 256, 0, stream>>>(
        Sc, AUD, 0, (long)SEQ * AUD, Vtb, AUD, 0, (long)DHEAD * AUD,
        Ctxb, HDIM, 0, DHEAD, nullptr, 1.0f, 2048, 128, 512, 0);
  }

  // O = Ctx @ Wo + bo : M=8192, f32 into d_out (cmode=2)
  transpose_k<<<tg, tb, 0, stream>>>(Wo, wT);
  gemm_bt<<<dim3(128, 128, 1), 256, 0, stream>>>(Ctx, HDIM, 0, 0, wT, HDIM, 0, 0,
                                                 out, HDIM, 0, 0, bo, 1.0f,
                                                 8192, 2048, 2048, 2);
  // out = LayerNorm(O + hs) * gamma + beta  (f32, in place over d_out)
  ln_k<<<8192, 256, 0, stream>>>(out, hs, gamma, beta, out);
}

// Round 6
// 820.600 us; speedup vs baseline: 3.7358x; 3.7358x over previous
//
#include <hip/hip_runtime.h>

#define HDIM 2048
#define NHEAD 16
#define DHEAD 128
#define BATCH 4
#define SEQ 2048
#define AUD 512

typedef unsigned short u16;
typedef unsigned int u32;
typedef __bf16 bf16_t;
typedef bf16_t bf16x8 __attribute__((ext_vector_type(8)));
typedef short short8 __attribute__((ext_vector_type(8)));
typedef float f32x4 __attribute__((ext_vector_type(4)));

typedef const __attribute__((address_space(1))) u32 gas_u32;
typedef __attribute__((address_space(3))) u32 las_u32;

__device__ __forceinline__ float b2f(u16 h) {
  union { u32 u; float f; } v; v.u = ((u32)h) << 16; return v.f;
}
__device__ __forceinline__ u16 f2b(float f) {
  union { float f; u32 u; } v; v.f = f;
  u32 r = (v.u + 0x7FFFu + ((v.u >> 16) & 1u)) >> 16;  // RNE
  return (u16)r;
}

// ---------------- f32 -> bf16 elementwise convert, 8 els/thread ----------------
__global__ __launch_bounds__(256) void cvt_k(const float* __restrict__ src,
                                             u16* __restrict__ dst, int n8) {
  int i = blockIdx.x * 256 + threadIdx.x;
  if (i >= n8) return;
  const float4* s4 = (const float4*)src;
  float4 a = s4[2 * i], b = s4[2 * i + 1];
  short8 o;
  o[0] = (short)f2b(a.x); o[1] = (short)f2b(a.y);
  o[2] = (short)f2b(a.z); o[3] = (short)f2b(a.w);
  o[4] = (short)f2b(b.x); o[5] = (short)f2b(b.y);
  o[6] = (short)f2b(b.z); o[7] = (short)f2b(b.w);
  *(short8*)(dst + (size_t)i * 8) = o;
}

// -------- weight transpose + convert: dst_bf16[n*2048 + k] = src_f32[k*2048 + n] --------
__global__ __launch_bounds__(256) void transpose_k(const float* __restrict__ src,
                                                   u16* __restrict__ dst) {
  __shared__ float tile[32][33];
  int tx = threadIdx.x, ty = threadIdx.y;        // 32 x 8
  int x = blockIdx.x * 32 + tx;
  int y0 = blockIdx.y * 32;
#pragma unroll
  for (int j = 0; j < 32; j += 8)
    tile[ty + j][tx] = src[(size_t)(y0 + ty + j) * HDIM + x];
  __syncthreads();
  int x2 = y0 + tx;
  int y2 = blockIdx.x * 32;
#pragma unroll
  for (int j = 0; j < 32; j += 8)
    dst[(size_t)(y2 + ty + j) * HDIM + x2] = f2b(tile[tx][ty + j]);
}

// ------------- m97-structure tiled GEMM: C = alpha*(A @ B + bias) -------------
// A: [M,K] bf16 row-major (lda); Bt: [N,K] bf16 row-major (ldb).
// 128x128 C-tile / block (256 thr); BK=32; LDS staging via global_load_lds w=16.
// Requires M%128==0, N%128==0, K%32==0, 16B-aligned A/Bt rows (lda/ldb mult of 8).
// batch z: ptr += (z>>4)*s?hi + (z&15)*s?lo (elements).
// cmode: 0 = bf16 C row-major; 1 = Vt scatter (bf16); 2 = f32 C row-major.
__global__ __launch_bounds__(256) void gemm_bt(
    const u16* __restrict__ A, int lda, long sAhi, long sAlo,
    const u16* __restrict__ Bt, int ldb, long sBhi, long sBlo,
    void* __restrict__ Cv, int ldc, long sChi, long sClo,
    const float* __restrict__ bias, float alpha, int M, int N, int K, int cmode) {
  __shared__ u16 As[128 * 32];  // [row][k] row-major, rows of 64B
  __shared__ u16 Bs[128 * 32];

  int z = blockIdx.z;
  A += (size_t)(z >> 4) * sAhi + (size_t)(z & 15) * sAlo;
  Bt += (size_t)(z >> 4) * sBhi + (size_t)(z & 15) * sBlo;
  size_t coff = (size_t)(z >> 4) * sChi + (size_t)(z & 15) * sClo;

  int lane = threadIdx.x & 63;
  int wave = threadIdx.x >> 6;
  int m0 = blockIdx.y * 128;
  int n0 = blockIdx.x * 128;
  int wm = (wave & 1) * 64;   // wave's 64x64 sub-block
  int wn = (wave >> 1) * 64;
  int row16 = lane & 15;
  int quad = lane >> 4;

  // staging geometry: 8 chunks of 1KB per tile; chunk = wave*2+t; lane i -> 16B
  int sr = (lane >> 2);        // row within 16-row chunk
  int sc = (lane & 3) * 8;     // k-offset (elements)

  f32x4 acc[4][4];
#pragma unroll
  for (int i = 0; i < 4; i++)
#pragma unroll
    for (int j = 0; j < 4; j++) acc[i][j] = (f32x4){0.f, 0.f, 0.f, 0.f};

  for (int k0 = 0; k0 < K; k0 += 32) {
#pragma unroll
    for (int t = 0; t < 2; t++) {
      int chunk = wave * 2 + t;
      int r = chunk * 16 + sr;
      const u16* ga = A + (size_t)(m0 + r) * lda + k0 + sc;
      const u16* gb = Bt + (size_t)(n0 + r) * ldb + k0 + sc;
      __builtin_amdgcn_global_load_lds((gas_u32*)ga, (las_u32*)(As + chunk * 512), 16, 0, 0);
      __builtin_amdgcn_global_load_lds((gas_u32*)gb, (las_u32*)(Bs + chunk * 512), 16, 0, 0);
    }
    __syncthreads();

    short8 af[4], bf[4];
#pragma unroll
    for (int mt = 0; mt < 4; mt++)
      af[mt] = *(const short8*)(As + (wm + mt * 16 + row16) * 32 + quad * 8);
#pragma unroll
    for (int nt = 0; nt < 4; nt++)
      bf[nt] = *(const short8*)(Bs + (wn + nt * 16 + row16) * 32 + quad * 8);
#pragma unroll
    for (int mt = 0; mt < 4; mt++)
#pragma unroll
      for (int nt = 0; nt < 4; nt++)
        acc[mt][nt] = __builtin_amdgcn_mfma_f32_16x16x32_bf16(
            __builtin_bit_cast(bf16x8, af[mt]), __builtin_bit_cast(bf16x8, bf[nt]),
            acc[mt][nt], 0, 0, 0);
    __syncthreads();
  }

  // epilogue: C/D frag layout col = lane&15, row = quad*4 + r
#pragma unroll
  for (int nt = 0; nt < 4; nt++) {
    int nn = n0 + wn + nt * 16 + row16;
    float bv = bias ? bias[nn] : 0.f;
#pragma unroll
    for (int mt = 0; mt < 4; mt++) {
#pragma unroll
      for (int r = 0; r < 4; r++) {
        int mm = m0 + wm + mt * 16 + quad * 4 + r;
        float val = (acc[mt][nt][r] + bv) * alpha;
        if (cmode == 2) {
          ((float*)Cv)[coff + (size_t)mm * ldc + nn] = val;
        } else if (cmode == 1) {
          int bb = mm >> 9, aa = mm & 511;
          int hh = nn >> 7, dd = nn & 127;
          ((u16*)Cv)[((size_t)((bb * 16 + hh) * 128 + dd)) * 512 + aa] = f2b(val);
        } else {
          ((u16*)Cv)[coff + (size_t)mm * ldc + nn] = f2b(val);
        }
      }
    }
  }
}

// ------- softmax over 512 keys, one wave per (h,q) row of ONE batch, in place -------
__global__ __launch_bounds__(256) void softmax_k(u16* __restrict__ Sc,
                                                 const float* __restrict__ mp) {
  int g = blockIdx.x * 4 + (threadIdx.x >> 6);  // 0 .. NH*SEQ-1
  int lane = threadIdx.x & 63;
  u16* rowp = Sc + (size_t)g * AUD;
  float s[8];
  float mx = -3.0e38f;
#pragma unroll
  for (int i = 0; i < 8; i++) {
    int a = lane + 64 * i;
    float v = b2f(rowp[a]) + mp[a] * (-10000.0f);
    s[i] = v;
    mx = fmaxf(mx, v);
  }
  for (int off = 32; off; off >>= 1) mx = fmaxf(mx, __shfl_xor(mx, off, 64));
  float sum = 0.f;
#pragma unroll
  for (int i = 0; i < 8; i++) {
    s[i] = __expf(s[i] - mx);
    sum += s[i];
  }
  for (int off = 32; off; off >>= 1) sum += __shfl_xor(sum, off, 64);
  float inv = 1.0f / sum;
#pragma unroll
  for (int i = 0; i < 8; i++) rowp[lane + 64 * i] = f2b(s[i] * inv);
}

// ---- residual + LayerNorm (f32 in/out): out = LN(O + hs)*gamma + beta, in place ----
__global__ __launch_bounds__(256) void ln_k(const float* O,
                                            const float* __restrict__ hs,
                                            const float* __restrict__ gamma,
                                            const float* __restrict__ beta,
                                            float* out) {
  size_t rowoff = (size_t)blockIdx.x * HDIM;
  float x[8], sum = 0.f, sq = 0.f;
#pragma unroll
  for (int i = 0; i < 8; i++) {
    int idx = threadIdx.x + 256 * i;
    float v = O[rowoff + idx] + hs[rowoff + idx];
    x[i] = v;
    sum += v;
    sq += v * v;
  }
  for (int off = 32; off; off >>= 1) {
    sum += __shfl_xor(sum, off, 64);
    sq += __shfl_xor(sq, off, 64);
  }
  __shared__ float red[8];
  int wave = threadIdx.x >> 6, lane = threadIdx.x & 63;
  if (lane == 0) { red[wave] = sum; red[4 + wave] = sq; }
  __syncthreads();
  sum = red[0] + red[1] + red[2] + red[3];
  sq = red[4] + red[5] + red[6] + red[7];
  float mu = sum * (1.0f / HDIM);
  float var = sq * (1.0f / HDIM) - mu * mu;
  float inv = rsqrtf(var + 1e-5f);
#pragma unroll
  for (int i = 0; i < 8; i++) {
    int idx = threadIdx.x + 256 * i;
    out[rowoff + idx] = (x[i] - mu) * inv * gamma[idx] + beta[idx];
  }
}

extern "C" void kernel_launch(void* const* d_in, const int* in_sizes, int n_in,
                              void* d_out, int out_size, void* d_ws, size_t ws_size,
                              hipStream_t stream) {
  (void)in_sizes; (void)n_in; (void)out_size; (void)ws_size;
  const float* hs   = (const float*)d_in[0];
  const float* at   = (const float*)d_in[1];
  const float* mask = (const float*)d_in[2];
  const float* Wq = (const float*)d_in[3];  const float* bq = (const float*)d_in[4];
  const float* Wk = (const float*)d_in[5];  const float* bk = (const float*)d_in[6];
  const float* Wv = (const float*)d_in[7];  const float* bv = (const float*)d_in[8];
  const float* Wo = (const float*)d_in[9];  const float* bo = (const float*)d_in[10];
  const float* gamma = (const float*)d_in[11];
  const float* beta  = (const float*)d_in[12];
  float* out = (float*)d_out;
  u16* ws = (u16*)d_ws;

  // workspace (bf16 elements). Total 83,886,080 els = 167.8 MB (ws has 256 MB).
  u16* hsb = ws;               // 16,777,216  bf16(hidden_states)
  u16* atb = ws + 16777216;    //  4,194,304  bf16(audio_tokens)
  u16* wT  = ws + 20971520;    //  4,194,304  transposed bf16 weight (reused 4x)
  u16* Q   = ws + 25165824;    // 16,777,216  (8192 x 2048)
  u16* Kb  = ws + 41943040;    //  4,194,304  (2048 x 2048)
  u16* Vt  = ws + 46137344;    //  4,194,304  [b,h,d,a]
  u16* Sc  = ws + 50331648;    // 16,777,216  (one batch: [h,q,a])
  u16* Ctx = ws + 67108864;    // 16,777,216  (8192 x 2048)
  // O (pre-LN, f32) lives in d_out; ln_k is same-thread in-place: safe.

  cvt_k<<<8192, 256, 0, stream>>>(hs, hsb, 2097152);
  cvt_k<<<2048, 256, 0, stream>>>(at, atb, 524288);

  dim3 tb(32, 8), tg(64, 64);
  const float qscale = 0.08838834764831845f;  // 1/sqrt(128)

  // Q = (hs @ Wq + bq) * qscale : M=8192 N=2048 K=2048
  transpose_k<<<tg, tb, 0, stream>>>(Wq, wT);
  gemm_bt<<<dim3(16, 64, 1), 256, 0, stream>>>(hsb, HDIM, 0, 0, wT, HDIM, 0, 0,
                                               Q, HDIM, 0, 0, bq, qscale,
                                               8192, 2048, 2048, 0);
  // K = at @ Wk + bk : M=2048
  transpose_k<<<tg, tb, 0, stream>>>(Wk, wT);
  gemm_bt<<<dim3(16, 16, 1), 256, 0, stream>>>(atb, HDIM, 0, 0, wT, HDIM, 0, 0,
                                               Kb, HDIM, 0, 0, bk, 1.0f,
                                               2048, 2048, 2048, 0);
  // V = at @ Wv + bv, written transposed per head into Vt
  transpose_k<<<tg, tb, 0, stream>>>(Wv, wT);
  gemm_bt<<<dim3(16, 16, 1), 256, 0, stream>>>(atb, HDIM, 0, 0, wT, HDIM, 0, 0,
                                               Vt, HDIM, 0, 0, bv, 1.0f,
                                               2048, 2048, 2048, 1);

  // attention per batch (Sc holds one batch at a time)
  for (int b = 0; b < BATCH; b++) {
    const u16* Qb = Q + (size_t)b * SEQ * HDIM;
    const u16* Kbb = Kb + (size_t)b * AUD * HDIM;
    const u16* Vtb = Vt + (size_t)b * NHEAD * DHEAD * AUD;
    u16* Ctxb = Ctx + (size_t)b * SEQ * HDIM;
    // scores[h] = Qh (2048x128) @ Kh^T : z = h, N=512, K=128
    gemm_bt<<<dim3(4, 16, NHEAD), 256, 0, stream>>>(
        Qb, HDIM, 0, DHEAD, Kbb, HDIM, 0, DHEAD,
        Sc, AUD, 0, (long)SEQ * AUD, nullptr, 1.0f, 2048, 512, 128, 0);
    // softmax rows (mask applied inside), in place
    softmax_k<<<NHEAD * SEQ / 4, 256, 0, stream>>>(Sc, mask + b * AUD);
    // ctx[h] = P (2048x512) @ V (512x128), BT = Vt rows : N=128, K=512
    gemm_bt<<<dim3(1, 16, NHEAD), 256, 0, stream>>>(
        Sc, AUD, 0, (long)SEQ * AUD, Vtb, AUD, 0, (long)DHEAD * AUD,
        Ctxb, HDIM, 0, DHEAD, nullptr, 1.0f, 2048, 128, 512, 0);
  }

  // O = Ctx @ Wo + bo : M=8192, f32 into d_out (cmode=2)
  transpose_k<<<tg, tb, 0, stream>>>(Wo, wT);
  gemm_bt<<<dim3(16, 64, 1), 256, 0, stream>>>(Ctx, HDIM, 0, 0, wT, HDIM, 0, 0,
                                               out, HDIM, 0, 0, bo, 1.0f,
                                               8192, 2048, 2048, 2);
  // out = LayerNorm(O + hs) * gamma + beta  (f32, in place over d_out)
  ln_k<<<8192, 256, 0, stream>>>(out, hs, gamma, beta, out);
}

// Round 7
// 687.204 us; speedup vs baseline: 4.4609x; 1.1941x over previous
//
#include <hip/hip_runtime.h>

#define HDIM 2048
#define NHEAD 16
#define DHEAD 128
#define BATCH 4
#define SEQ 2048
#define AUD 512

typedef unsigned short u16;
typedef unsigned int u32;
typedef __bf16 bf16_t;
typedef bf16_t bf16x8 __attribute__((ext_vector_type(8)));
typedef short short8 __attribute__((ext_vector_type(8)));
typedef float f32x4 __attribute__((ext_vector_type(4)));

typedef const __attribute__((address_space(1))) u32 gas_u32;
typedef __attribute__((address_space(3))) u32 las_u32;

__device__ __forceinline__ float b2f(u16 h) {
  union { u32 u; float f; } v; v.u = ((u32)h) << 16; return v.f;
}
__device__ __forceinline__ u16 f2b(float f) {
  union { float f; u32 u; } v; v.f = f;
  u32 r = (v.u + 0x7FFFu + ((v.u >> 16) & 1u)) >> 16;  // RNE
  return (u16)r;
}

// ---------------- f32 -> bf16 elementwise convert, 8 els/thread ----------------
__global__ __launch_bounds__(256) void cvt_k(const float* __restrict__ src,
                                             u16* __restrict__ dst, int n8) {
  int i = blockIdx.x * 256 + threadIdx.x;
  if (i >= n8) return;
  const float4* s4 = (const float4*)src;
  float4 a = s4[2 * i], b = s4[2 * i + 1];
  short8 o;
  o[0] = (short)f2b(a.x); o[1] = (short)f2b(a.y);
  o[2] = (short)f2b(a.z); o[3] = (short)f2b(a.w);
  o[4] = (short)f2b(b.x); o[5] = (short)f2b(b.y);
  o[6] = (short)f2b(b.z); o[7] = (short)f2b(b.w);
  *(short8*)(dst + (size_t)i * 8) = o;
}

// -------- weight transpose + convert: dst_bf16[n*2048 + k] = src_f32[k*2048 + n] --------
__global__ __launch_bounds__(256) void transpose_k(const float* __restrict__ src,
                                                   u16* __restrict__ dst) {
  __shared__ float tile[32][33];
  int tx = threadIdx.x, ty = threadIdx.y;        // 32 x 8
  int x = blockIdx.x * 32 + tx;
  int y0 = blockIdx.y * 32;
#pragma unroll
  for (int j = 0; j < 32; j += 8)
    tile[ty + j][tx] = src[(size_t)(y0 + ty + j) * HDIM + x];
  __syncthreads();
  int x2 = y0 + tx;
  int y2 = blockIdx.x * 32;
#pragma unroll
  for (int j = 0; j < 32; j += 8)
    dst[(size_t)(y2 + ty + j) * HDIM + x2] = f2b(tile[tx][ty + j]);
}

// ------------- m97-structure tiled GEMM: C = alpha*(A @ B + bias) -------------
// A: [M,K] bf16 row-major (lda); Bt: [N,K] bf16 row-major (ldb).
// cmode: 0 = bf16 C row-major; 1 = Vt scatter (bf16); 2 = f32 C row-major.
__global__ __launch_bounds__(256) void gemm_bt(
    const u16* __restrict__ A, int lda,
    const u16* __restrict__ Bt, int ldb,
    void* __restrict__ Cv, int ldc,
    const float* __restrict__ bias, float alpha, int M, int N, int K, int cmode) {
  __shared__ u16 As[128 * 32];  // [row][k], rows of 64B
  __shared__ u16 Bs[128 * 32];

  int lane = threadIdx.x & 63;
  int wave = threadIdx.x >> 6;
  int m0 = blockIdx.y * 128;
  int n0 = blockIdx.x * 128;
  int wm = (wave & 1) * 64;
  int wn = (wave >> 1) * 64;
  int row16 = lane & 15;
  int quad = lane >> 4;

  int sr = (lane >> 2);
  int sc = (lane & 3) * 8;

  f32x4 acc[4][4];
#pragma unroll
  for (int i = 0; i < 4; i++)
#pragma unroll
    for (int j = 0; j < 4; j++) acc[i][j] = (f32x4){0.f, 0.f, 0.f, 0.f};

  for (int k0 = 0; k0 < K; k0 += 32) {
#pragma unroll
    for (int t = 0; t < 2; t++) {
      int chunk = wave * 2 + t;
      int r = chunk * 16 + sr;
      const u16* ga = A + (size_t)(m0 + r) * lda + k0 + sc;
      const u16* gb = Bt + (size_t)(n0 + r) * ldb + k0 + sc;
      __builtin_amdgcn_global_load_lds((gas_u32*)ga, (las_u32*)(As + chunk * 512), 16, 0, 0);
      __builtin_amdgcn_global_load_lds((gas_u32*)gb, (las_u32*)(Bs + chunk * 512), 16, 0, 0);
    }
    __syncthreads();

    short8 af[4], bf[4];
#pragma unroll
    for (int mt = 0; mt < 4; mt++)
      af[mt] = *(const short8*)(As + (wm + mt * 16 + row16) * 32 + quad * 8);
#pragma unroll
    for (int nt = 0; nt < 4; nt++)
      bf[nt] = *(const short8*)(Bs + (wn + nt * 16 + row16) * 32 + quad * 8);
#pragma unroll
    for (int mt = 0; mt < 4; mt++)
#pragma unroll
      for (int nt = 0; nt < 4; nt++)
        acc[mt][nt] = __builtin_amdgcn_mfma_f32_16x16x32_bf16(
            __builtin_bit_cast(bf16x8, af[mt]), __builtin_bit_cast(bf16x8, bf[nt]),
            acc[mt][nt], 0, 0, 0);
    __syncthreads();
  }

#pragma unroll
  for (int nt = 0; nt < 4; nt++) {
    int nn = n0 + wn + nt * 16 + row16;
    float bv = bias ? bias[nn] : 0.f;
#pragma unroll
    for (int mt = 0; mt < 4; mt++) {
#pragma unroll
      for (int r = 0; r < 4; r++) {
        int mm = m0 + wm + mt * 16 + quad * 4 + r;
        float val = (acc[mt][nt][r] + bv) * alpha;
        if (cmode == 2) {
          ((float*)Cv)[(size_t)mm * ldc + nn] = val;
        } else if (cmode == 1) {
          int bb = mm >> 9, aa = mm & 511;
          int hh = nn >> 7, dd = nn & 127;
          ((u16*)Cv)[((size_t)((bb * 16 + hh) * 128 + dd)) * 512 + aa] = f2b(val);
        } else {
          ((u16*)Cv)[(size_t)mm * ldc + nn] = f2b(val);
        }
      }
    }
  }
}

// ---------------- fused flash attention ----------------
// grid (SEQ/128, BATCH*NHEAD), 256 thr. Q pre-scaled by 1/sqrt(DH).
// Q:[B*SEQ][HDIM] bf16; K:[B*AUD][HDIM] bf16; Vt:[b,h,d,a] bf16; mask:[B][AUD] f32.
// Ctx:[B*SEQ][HDIM] bf16. No-max-sub softmax: e = exp(s + m*-1e4); O = (P@V)/l.
// Wave owns 32 q-rows x all keys -> l is wave-local. P round-trips via LDS (KP reuse).
__global__ __launch_bounds__(256) void flash_k(
    const u16* __restrict__ Q, const u16* __restrict__ K,
    const u16* __restrict__ Vt, const float* __restrict__ mask,
    u16* __restrict__ Ctx) {
  __shared__ u16 KP[128 * 128];  // K-tile [key][dh], then P-tile [q][key]
  __shared__ u16 Vs[128 * 128];  // V-tile [dh][key]

  int bh = blockIdx.y, b = bh >> 4, h = bh & 15;
  int q0 = blockIdx.x * 128;
  int lane = threadIdx.x & 63, wave = threadIdx.x >> 6;
  int row16 = lane & 15, quad = lane >> 4;
  int wq = wave * 32;  // wave's 32 q-rows

  const u16* qbase = Q + ((size_t)(b * SEQ + q0)) * HDIM + h * DHEAD;
  const u16* kbase = K + ((size_t)b * AUD) * HDIM + h * DHEAD;
  const u16* vbase = Vt + ((size_t)(b * NHEAD + h)) * DHEAD * AUD;
  const float* mp = mask + b * AUD;

  // Q fragments in registers: 2 m-tiles x 4 k-steps
  short8 qf[2][4];
#pragma unroll
  for (int mt = 0; mt < 2; mt++)
#pragma unroll
    for (int ks = 0; ks < 4; ks++)
      qf[mt][ks] = *(const short8*)(qbase + (size_t)(wq + mt * 16 + row16) * HDIM +
                                    ks * 32 + quad * 8);

  f32x4 oacc[2][8];
  float lacc[2][4];
#pragma unroll
  for (int mt = 0; mt < 2; mt++) {
#pragma unroll
    for (int nt = 0; nt < 8; nt++) oacc[mt][nt] = (f32x4){0.f, 0.f, 0.f, 0.f};
#pragma unroll
    for (int r = 0; r < 4; r++) lacc[mt][r] = 0.f;
  }

  int sl = (lane >> 4);        // staging: row within 4-row chunk
  int scol = (lane & 15) * 8;  // k/els offset (16B)

  for (int kt = 0; kt < 4; kt++) {
    // stage K-tile (128 keys x 128 dh) and V-tile (128 dh x 128 keys)
#pragma unroll
    for (int t = 0; t < 8; t++) {
      int c = wave * 8 + t;
      int r = c * 4 + sl;
      __builtin_amdgcn_global_load_lds(
          (gas_u32*)(kbase + (size_t)(kt * 128 + r) * HDIM + scol),
          (las_u32*)(KP + c * 512), 16, 0, 0);
      __builtin_amdgcn_global_load_lds(
          (gas_u32*)(vbase + (size_t)r * AUD + kt * 128 + scol),
          (las_u32*)(Vs + c * 512), 16, 0, 0);
    }
    __syncthreads();

    // S = Q @ K^T : wave's 32q x 128key
    f32x4 sacc[2][8];
#pragma unroll
    for (int mt = 0; mt < 2; mt++)
#pragma unroll
      for (int nt = 0; nt < 8; nt++) sacc[mt][nt] = (f32x4){0.f, 0.f, 0.f, 0.f};
#pragma unroll
    for (int ks = 0; ks < 4; ks++) {
      short8 bf[8];
#pragma unroll
      for (int nt = 0; nt < 8; nt++)
        bf[nt] = *(const short8*)(KP + (nt * 16 + row16) * 128 + ks * 32 + quad * 8);
#pragma unroll
      for (int mt = 0; mt < 2; mt++)
#pragma unroll
        for (int nt = 0; nt < 8; nt++)
          sacc[mt][nt] = __builtin_amdgcn_mfma_f32_16x16x32_bf16(
              __builtin_bit_cast(bf16x8, qf[mt][ks]), __builtin_bit_cast(bf16x8, bf[nt]),
              sacc[mt][nt], 0, 0, 0);
    }

    // e = exp(s + mask*-1e4); accumulate l
#pragma unroll
    for (int nt = 0; nt < 8; nt++) {
      float mval = mp[kt * 128 + nt * 16 + row16] * (-10000.0f);
#pragma unroll
      for (int mt = 0; mt < 2; mt++)
#pragma unroll
        for (int r = 0; r < 4; r++) {
          float e = __expf(sacc[mt][nt][r] + mval);
          sacc[mt][nt][r] = e;
          lacc[mt][r] += e;
        }
    }
    __syncthreads();  // all waves done reading KP

    // write P (bf16) into KP as [q][key]
#pragma unroll
    for (int mt = 0; mt < 2; mt++)
#pragma unroll
      for (int nt = 0; nt < 8; nt++)
#pragma unroll
        for (int r = 0; r < 4; r++)
          KP[(wq + mt * 16 + quad * 4 + r) * 128 + nt * 16 + row16] =
              f2b(sacc[mt][nt][r]);
    __syncthreads();

    // O += P @ V : A = P [q][key], B = Vs rows [dh][key]
#pragma unroll
    for (int ks = 0; ks < 4; ks++) {
      short8 af[2], bf[8];
#pragma unroll
      for (int mt = 0; mt < 2; mt++)
        af[mt] = *(const short8*)(KP + (wq + mt * 16 + row16) * 128 + ks * 32 + quad * 8);
#pragma unroll
      for (int nt = 0; nt < 8; nt++)
        bf[nt] = *(const short8*)(Vs + (nt * 16 + row16) * 128 + ks * 32 + quad * 8);
#pragma unroll
      for (int mt = 0; mt < 2; mt++)
#pragma unroll
        for (int nt = 0; nt < 8; nt++)
          oacc[mt][nt] = __builtin_amdgcn_mfma_f32_16x16x32_bf16(
              __builtin_bit_cast(bf16x8, af[mt]), __builtin_bit_cast(bf16x8, bf[nt]),
              oacc[mt][nt], 0, 0, 0);
    }
    __syncthreads();  // done reading KP/Vs before next stage
  }

  // reduce l over the 16 lanes of each quad (keys dimension)
#pragma unroll
  for (int mt = 0; mt < 2; mt++)
#pragma unroll
    for (int r = 0; r < 4; r++) {
      float s = lacc[mt][r];
      for (int off = 1; off < 16; off <<= 1) s += __shfl_xor(s, off, 64);
      lacc[mt][r] = 1.0f / s;
    }

  // write ctx: C/D layout col=dh (lane&15), row=q (quad*4+r)
  u16* cb = Ctx + ((size_t)(b * SEQ + q0 + wq)) * HDIM + h * DHEAD;
#pragma unroll
  for (int mt = 0; mt < 2; mt++)
#pragma unroll
    for (int nt = 0; nt < 8; nt++)
#pragma unroll
      for (int r = 0; r < 4; r++)
        cb[(size_t)(mt * 16 + quad * 4 + r) * HDIM + nt * 16 + row16] =
            f2b(oacc[mt][nt][r] * lacc[mt][r]);
}

// ---- residual + LayerNorm (f32 in/out): out = LN(O + hs)*gamma + beta, in place ----
__global__ __launch_bounds__(256) void ln_k(const float* O,
                                            const float* __restrict__ hs,
                                            const float* __restrict__ gamma,
                                            const float* __restrict__ beta,
                                            float* out) {
  size_t rowoff = (size_t)blockIdx.x * HDIM;
  float x[8], sum = 0.f, sq = 0.f;
#pragma unroll
  for (int i = 0; i < 8; i++) {
    int idx = threadIdx.x + 256 * i;
    float v = O[rowoff + idx] + hs[rowoff + idx];
    x[i] = v;
    sum += v;
    sq += v * v;
  }
  for (int off = 32; off; off >>= 1) {
    sum += __shfl_xor(sum, off, 64);
    sq += __shfl_xor(sq, off, 64);
  }
  __shared__ float red[8];
  int wave = threadIdx.x >> 6, lane = threadIdx.x & 63;
  if (lane == 0) { red[wave] = sum; red[4 + wave] = sq; }
  __syncthreads();
  sum = red[0] + red[1] + red[2] + red[3];
  sq = red[4] + red[5] + red[6] + red[7];
  float mu = sum * (1.0f / HDIM);
  float var = sq * (1.0f / HDIM) - mu * mu;
  float inv = rsqrtf(var + 1e-5f);
#pragma unroll
  for (int i = 0; i < 8; i++) {
    int idx = threadIdx.x + 256 * i;
    out[rowoff + idx] = (x[i] - mu) * inv * gamma[idx] + beta[idx];
  }
}

extern "C" void kernel_launch(void* const* d_in, const int* in_sizes, int n_in,
                              void* d_out, int out_size, void* d_ws, size_t ws_size,
                              hipStream_t stream) {
  (void)in_sizes; (void)n_in; (void)out_size; (void)ws_size;
  const float* hs   = (const float*)d_in[0];
  const float* at   = (const float*)d_in[1];
  const float* mask = (const float*)d_in[2];
  const float* Wq = (const float*)d_in[3];  const float* bq = (const float*)d_in[4];
  const float* Wk = (const float*)d_in[5];  const float* bk = (const float*)d_in[6];
  const float* Wv = (const float*)d_in[7];  const float* bv = (const float*)d_in[8];
  const float* Wo = (const float*)d_in[9];  const float* bo = (const float*)d_in[10];
  const float* gamma = (const float*)d_in[11];
  const float* beta  = (const float*)d_in[12];
  float* out = (float*)d_out;
  u16* ws = (u16*)d_ws;

  // workspace (bf16 elements). Total 67,108,864 els = 134.2 MB (ws has 256 MB).
  u16* hsb = ws;               // 16,777,216  bf16(hidden_states)
  u16* atb = ws + 16777216;    //  4,194,304  bf16(audio_tokens)
  u16* wT  = ws + 20971520;    //  4,194,304  transposed bf16 weight (reused 4x)
  u16* Q   = ws + 25165824;    // 16,777,216  (8192 x 2048, pre-scaled)
  u16* Kb  = ws + 41943040;    //  4,194,304  (2048 x 2048)
  u16* Vt  = ws + 46137344;    //  4,194,304  [b,h,d,a]
  u16* Ctx = ws + 50331648;    // 16,777,216  (8192 x 2048)
  // O (pre-LN, f32) lives in d_out; ln_k is same-thread in-place: safe.

  cvt_k<<<8192, 256, 0, stream>>>(hs, hsb, 2097152);
  cvt_k<<<2048, 256, 0, stream>>>(at, atb, 524288);

  dim3 tb(32, 8), tg(64, 64);
  const float qscale = 0.08838834764831845f;  // 1/sqrt(128)

  // Q = (hs @ Wq + bq) * qscale : M=8192 N=2048 K=2048
  transpose_k<<<tg, tb, 0, stream>>>(Wq, wT);
  gemm_bt<<<dim3(16, 64), 256, 0, stream>>>(hsb, HDIM, wT, HDIM, Q, HDIM,
                                            bq, qscale, 8192, 2048, 2048, 0);
  // K = at @ Wk + bk : M=2048
  transpose_k<<<tg, tb, 0, stream>>>(Wk, wT);
  gemm_bt<<<dim3(16, 16), 256, 0, stream>>>(atb, HDIM, wT, HDIM, Kb, HDIM,
                                            bk, 1.0f, 2048, 2048, 2048, 0);
  // V = at @ Wv + bv, written transposed per head into Vt
  transpose_k<<<tg, tb, 0, stream>>>(Wv, wT);
  gemm_bt<<<dim3(16, 16), 256, 0, stream>>>(atb, HDIM, wT, HDIM, Vt, HDIM,
                                            bv, 1.0f, 2048, 2048, 2048, 1);

  // fused attention: Ctx = softmax(Q K^T + mask) V  (all batches/heads, one launch)
  flash_k<<<dim3(SEQ / 128, BATCH * NHEAD), 256, 0, stream>>>(Q, Kb, Vt, mask, Ctx);

  // O = Ctx @ Wo + bo : M=8192, f32 into d_out (cmode=2)
  transpose_k<<<tg, tb, 0, stream>>>(Wo, wT);
  gemm_bt<<<dim3(16, 64), 256, 0, stream>>>(Ctx, HDIM, wT, HDIM, out, HDIM,
                                            bo, 1.0f, 8192, 2048, 2048, 2);
  // out = LayerNorm(O + hs) * gamma + beta  (f32, in place over d_out)
  ln_k<<<8192, 256, 0, stream>>>(out, hs, gamma, beta, out);
}